// Round 1
// baseline (115.885 us; speedup 1.0000x reference)
//
#include <hip/hip_runtime.h>

#define NB 256      // batch
#define S  32       // boxes per sample
#define NL 24       // labels

__global__ __launch_bounds__(256) void layout_metric_kernel(
    const float* __restrict__ pred_left,
    const float* __restrict__ pred_top,
    const float* __restrict__ pred_width,
    const float* __restrict__ pred_height,
    const float* __restrict__ pred_label,
    const int* __restrict__ true_left,
    const int* __restrict__ true_top,
    const int* __restrict__ true_width,
    const int* __restrict__ true_height,
    const int* __restrict__ true_label,
    const int* __restrict__ true_length,
    const int* __restrict__ pred_length,
    float* __restrict__ out)
{
    const int b   = blockIdx.x;
    const int tid = threadIdx.x;

    __shared__ int s_arg[5][S];                        // argmax: l,t,w,h,label
    __shared__ int s_top[2][S], s_bot[2][S];
    __shared__ int s_lft[2][S], s_rgt[2][S];
    __shared__ int s_lab[2][S], s_val[2][S];
    __shared__ int s_cnt_t[NL], s_cnt_p[NL], s_inter[NL];

    // ---- 1) argmax of the 5 pred logit tensors (first-max tie-break) ----
    if (tid < 5 * S) {
        const int type = tid >> 5;    // 0..4
        const int j    = tid & 31;
        const float* base;
        int n = 64;
        if      (type == 0) base = pred_left;
        else if (type == 1) base = pred_top;
        else if (type == 2) base = pred_width;
        else if (type == 3) base = pred_height;
        else               { base = pred_label; n = NL; }
        const float* row = base + ((size_t)b * S + j) * n;
        float best = row[0];
        int   bi   = 0;
        for (int k = 1; k < n; ++k) {
            float v = row[k];
            if (v > best) { best = v; bi = k; }   // strict > == first occurrence
        }
        s_arg[type][j] = bi;
    }
    if (tid < NL) { s_cnt_t[tid] = 0; s_cnt_p[tid] = 0; s_inter[tid] = 0; }
    __syncthreads();

    // ---- 2) box params for both maps (m=0 true, m=1 pred) ----
    if (tid < 2 * S) {
        const int m = tid >> 5;
        const int j = tid & 31;
        int l, t, w, h, lab, len;
        if (m == 0) {
            l   = true_left  [b * S + j];
            t   = true_top   [b * S + j];
            w   = true_width [b * S + j];
            h   = true_height[b * S + j];
            lab = true_label [b * S + j];
            len = true_length[b];
        } else {
            l   = s_arg[0][j];
            t   = s_arg[1][j];
            w   = s_arg[2][j];
            h   = s_arg[3][j];
            lab = s_arg[4][j];
            len = pred_length[b];
        }
        const int r  = min(63, l + w);
        const int bo = min(63, t + h);
        s_top[m][j] = t;  s_bot[m][j] = bo;
        s_lft[m][j] = l;  s_rgt[m][j] = r;
        s_lab[m][j] = lab;
        s_val[m][j] = (j < len) && (t < bo) && (l < r);
    }
    __syncthreads();

    // ---- 3) rasterize both maps, count per-label stats ----
    for (int p = tid; p < 64 * 64; p += 256) {
        const int y = p >> 6;
        const int x = p & 63;
        int vals[2];
        #pragma unroll
        for (int m = 0; m < 2; ++m) {
            int v = 0;                              // DEFAULT_LABEL
            for (int j = S - 1; j >= 0; --j) {      // last valid box wins
                if (s_val[m][j] &&
                    s_top[m][j] <= y && y <= s_bot[m][j] &&
                    s_lft[m][j] <= x && x <= s_rgt[m][j]) {
                    v = s_lab[m][j];
                    break;
                }
            }
            vals[m] = v;
        }
        atomicAdd(&s_cnt_t[vals[0]], 1);
        atomicAdd(&s_cnt_p[vals[1]], 1);
        if (vals[0] == vals[1]) atomicAdd(&s_inter[vals[0]], 1);
    }
    __syncthreads();

    // ---- 4) reduce 24 labels, write acc / miou ----
    if (tid == 0) {
        int   it = 0;
        float ws = 0.f, wi = 0.f;
        for (int L = 0; L < NL; ++L) {
            const int inter = s_inter[L];
            const int un    = s_cnt_t[L] + s_cnt_p[L] - inter;
            it += inter;
            if (un > 0) {
                ws += 1.f;
                wi += (float)inter / ((float)un + 1e-9f);
            }
        }
        out[b]      = (float)it / 4096.0f;   // acc
        out[NB + b] = wi / ws;               // miou
    }
}

extern "C" void kernel_launch(void* const* d_in, const int* in_sizes, int n_in,
                              void* d_out, int out_size, void* d_ws, size_t ws_size,
                              hipStream_t stream) {
    const float* pred_left   = (const float*)d_in[0];
    const float* pred_top    = (const float*)d_in[1];
    const float* pred_width  = (const float*)d_in[2];
    const float* pred_height = (const float*)d_in[3];
    const float* pred_label  = (const float*)d_in[4];
    const int*   true_left   = (const int*)d_in[5];
    const int*   true_top    = (const int*)d_in[6];
    const int*   true_width  = (const int*)d_in[7];
    const int*   true_height = (const int*)d_in[8];
    const int*   true_label  = (const int*)d_in[9];
    const int*   true_length = (const int*)d_in[10];
    const int*   pred_length = (const int*)d_in[11];
    float* out = (float*)d_out;

    layout_metric_kernel<<<NB, 256, 0, stream>>>(
        pred_left, pred_top, pred_width, pred_height, pred_label,
        true_left, true_top, true_width, true_height, true_label,
        true_length, pred_length, out);
}

// Round 2
// 15.484 us; speedup vs baseline: 7.4840x; 7.4840x over previous
//
#include <hip/hip_runtime.h>

#define NB 256      // batch
#define S  32       // boxes per sample
#define NL 24       // labels

__global__ __launch_bounds__(256) void layout_metric_kernel(
    const float* __restrict__ pred_left,
    const float* __restrict__ pred_top,
    const float* __restrict__ pred_width,
    const float* __restrict__ pred_height,
    const float* __restrict__ pred_label,
    const int* __restrict__ true_left,
    const int* __restrict__ true_top,
    const int* __restrict__ true_width,
    const int* __restrict__ true_height,
    const int* __restrict__ true_label,
    const int* __restrict__ true_length,
    const int* __restrict__ pred_length,
    float* __restrict__ out)
{
    const int b   = blockIdx.x;
    const int tid = threadIdx.x;

    __shared__ int s_arg[5][S];                         // argmax: l,t,w,h,label
    __shared__ unsigned long long s_xmask[2][S];        // per-box x coverage mask
    __shared__ unsigned int s_meta[2][S];               // valid<<31|top<<12|bot<<6|lab
    __shared__ unsigned long long s_M[2][64][NL];       // per (map,row,label) masks
    __shared__ int s_cnt[3][NL];                        // ct, cp, inter

    // ---- Phase 1: argmax of the 5 pred logit tensors (first-max tie-break) ----
    if (tid < 5 * S) {
        const int type = tid >> 5;    // 0..4
        const int j    = tid & 31;
        float best = -3.402823466e38f;
        int   bi   = 0;
        if (type < 4) {
            const float* base = (type == 0) ? pred_left
                              : (type == 1) ? pred_top
                              : (type == 2) ? pred_width
                                            : pred_height;
            const float4* r4 = (const float4*)(base + ((size_t)b * S + j) * 64);
            #pragma unroll
            for (int k = 0; k < 16; ++k) {
                float4 v = r4[k];
                if (v.x > best) { best = v.x; bi = 4 * k + 0; }
                if (v.y > best) { best = v.y; bi = 4 * k + 1; }
                if (v.z > best) { best = v.z; bi = 4 * k + 2; }
                if (v.w > best) { best = v.w; bi = 4 * k + 3; }
            }
        } else {
            const float4* r4 = (const float4*)(pred_label + ((size_t)b * S + j) * NL);
            #pragma unroll
            for (int k = 0; k < 6; ++k) {
                float4 v = r4[k];
                if (v.x > best) { best = v.x; bi = 4 * k + 0; }
                if (v.y > best) { best = v.y; bi = 4 * k + 1; }
                if (v.z > best) { best = v.z; bi = 4 * k + 2; }
                if (v.w > best) { best = v.w; bi = 4 * k + 3; }
            }
        }
        s_arg[type][j] = bi;
    }

    // zero the mask array (3072 u64) and counters
    {
        unsigned long long* mflat = &s_M[0][0][0];
        #pragma unroll
        for (int k = 0; k < 12; ++k) mflat[tid + k * 256] = 0ull;
        if (tid < 3 * NL) (&s_cnt[0][0])[tid] = 0;
    }
    __syncthreads();

    // ---- Phase 2: box setup for both maps (m=0 true, m=1 pred) ----
    if (tid < 2 * S) {
        const int m = tid >> 5;
        const int j = tid & 31;
        int l, t, w, h, lab, len;
        if (m == 0) {
            l   = true_left  [b * S + j];
            t   = true_top   [b * S + j];
            w   = true_width [b * S + j];
            h   = true_height[b * S + j];
            lab = true_label [b * S + j];
            len = true_length[b];
        } else {
            l   = s_arg[0][j];
            t   = s_arg[1][j];
            w   = s_arg[2][j];
            h   = s_arg[3][j];
            lab = s_arg[4][j];
            len = pred_length[b];
        }
        const int r  = min(63, l + w);
        const int bo = min(63, t + h);
        const bool val = (j < len) && (t < bo) && (l < r);
        unsigned long long xm = 0ull;
        if (val) xm = (~0ull << l) & (~0ull >> (63 - r));   // l<=62, r>=1 when valid
        s_xmask[m][j] = xm;
        s_meta[m][j]  = (val ? 0x80000000u : 0u) |
                        ((unsigned)t << 12) | ((unsigned)bo << 6) | (unsigned)lab;
    }
    __syncthreads();

    // ---- Phase 3: painter's sweep per (map,row) → per-label masks ----
    if (tid < 128) {
        const int m = tid >> 6;
        const int y = tid & 63;
        unsigned long long rem = ~0ull;
        #pragma unroll
        for (int j = S - 1; j >= 0; --j) {
            const unsigned int md = s_meta[m][j];
            if (md & 0x80000000u) {
                const int top = (md >> 12) & 63;
                const int bot = (md >> 6)  & 63;
                if (top <= y && y <= bot) {
                    const unsigned long long cov = s_xmask[m][j] & rem;
                    if (cov) {
                        rem &= ~cov;
                        s_M[m][y][md & 31] |= cov;
                    }
                }
            }
        }
        if (rem) s_M[m][y][0] |= rem;   // DEFAULT_LABEL = 0
    }
    __syncthreads();

    // ---- Phase 4: popcount reduction per label ----
    if (tid < 8 * NL) {
        const int L  = tid >> 3;   // 0..23
        const int rg = tid & 7;    // 8 rows each
        int ct = 0, cp = 0, ci = 0;
        #pragma unroll
        for (int i = 0; i < 8; ++i) {
            const int y = rg * 8 + i;
            const unsigned long long tm = s_M[0][y][L];
            const unsigned long long pm = s_M[1][y][L];
            ct += __popcll(tm);
            cp += __popcll(pm);
            ci += __popcll(tm & pm);
        }
        atomicAdd(&s_cnt[0][L], ct);
        atomicAdd(&s_cnt[1][L], cp);
        atomicAdd(&s_cnt[2][L], ci);
    }
    __syncthreads();

    // ---- Phase 5: final metrics ----
    if (tid == 0) {
        int   it = 0;
        float ws = 0.f, wi = 0.f;
        #pragma unroll
        for (int L = 0; L < NL; ++L) {
            const int ct = s_cnt[0][L];
            const int cp = s_cnt[1][L];
            const int ci = s_cnt[2][L];
            const int un = ct + cp - ci;
            it += ci;
            if (un > 0) {
                ws += 1.f;
                wi += (float)ci / ((float)un + 1e-9f);
            }
        }
        out[b]      = (float)it / 4096.0f;   // acc
        out[NB + b] = wi / ws;               // miou
    }
}

extern "C" void kernel_launch(void* const* d_in, const int* in_sizes, int n_in,
                              void* d_out, int out_size, void* d_ws, size_t ws_size,
                              hipStream_t stream) {
    const float* pred_left   = (const float*)d_in[0];
    const float* pred_top    = (const float*)d_in[1];
    const float* pred_width  = (const float*)d_in[2];
    const float* pred_height = (const float*)d_in[3];
    const float* pred_label  = (const float*)d_in[4];
    const int*   true_left   = (const int*)d_in[5];
    const int*   true_top    = (const int*)d_in[6];
    const int*   true_width  = (const int*)d_in[7];
    const int*   true_height = (const int*)d_in[8];
    const int*   true_label  = (const int*)d_in[9];
    const int*   true_length = (const int*)d_in[10];
    const int*   pred_length = (const int*)d_in[11];
    float* out = (float*)d_out;

    layout_metric_kernel<<<NB, 256, 0, stream>>>(
        pred_left, pred_top, pred_width, pred_height, pred_label,
        true_left, true_top, true_width, true_height, true_label,
        true_length, pred_length, out);
}

// Round 3
// 13.071 us; speedup vs baseline: 8.8657x; 1.1846x over previous
//
#include <hip/hip_runtime.h>

#define NB 256      // batch
#define S  32       // boxes per sample
#define NL 24       // labels

__global__ __launch_bounds__(512) void layout_metric_kernel(
    const float* __restrict__ pred_left,
    const float* __restrict__ pred_top,
    const float* __restrict__ pred_width,
    const float* __restrict__ pred_height,
    const float* __restrict__ pred_label,
    const int* __restrict__ true_left,
    const int* __restrict__ true_top,
    const int* __restrict__ true_width,
    const int* __restrict__ true_height,
    const int* __restrict__ true_label,
    const int* __restrict__ true_length,
    const int* __restrict__ pred_length,
    float* __restrict__ out)
{
    const int b   = blockIdx.x;
    const int tid = threadIdx.x;

    __shared__ int s_arg[5][S];                         // argmax: l,t,w,h,label
    __shared__ unsigned long long s_xmask[2][S];        // per-box x coverage mask
    __shared__ unsigned int s_meta[2][S];               // valid<<31|top<<12|bot<<6|lab
    __shared__ unsigned long long s_M[2][64][NL];       // per (map,row,label) masks
    __shared__ int s_cnt[3][NL];                        // ct, cp, inter

    // ---- Phase 1 (pre-barrier, disjoint waves) ----
    // waves 0-3: argmax of the four 64-wide logit tensors, 2 threads per row
    if (tid < 256) {
        const int type = tid >> 6;          // 0..3
        const int j    = (tid >> 1) & 31;   // box row
        const int half = tid & 1;           // which 32-element half
        const float* base = (type == 0) ? pred_left
                          : (type == 1) ? pred_top
                          : (type == 2) ? pred_width
                                        : pred_height;
        const float4* r4 = (const float4*)(base + ((size_t)b * S + j) * 64) + half * 8;
        float best = -3.402823466e38f;
        int   bi   = half * 32;
        #pragma unroll
        for (int k = 0; k < 8; ++k) {
            float4 v = r4[k];
            const int o = half * 32 + 4 * k;
            if (v.x > best) { best = v.x; bi = o + 0; }
            if (v.y > best) { best = v.y; bi = o + 1; }
            if (v.z > best) { best = v.z; bi = o + 2; }
            if (v.w > best) { best = v.w; bi = o + 3; }
        }
        // merge the two halves (lanes tid, tid^1 are in the same wave)
        const float ob = __shfl_xor(best, 1);
        const int   oi = __shfl_xor(bi, 1);
        if (half == 0) {
            if (ob > best) { bi = oi; }     // strict >: low half wins ties
            s_arg[type][j] = bi;
        }
    } else if (tid < 288) {
        // wave 4 lanes 0-31: label argmax (24-wide)
        const int j = tid - 256;
        const float4* r4 = (const float4*)(pred_label + ((size_t)b * S + j) * NL);
        float best = -3.402823466e38f;
        int   bi   = 0;
        #pragma unroll
        for (int k = 0; k < 6; ++k) {
            float4 v = r4[k];
            if (v.x > best) { best = v.x; bi = 4 * k + 0; }
            if (v.y > best) { best = v.y; bi = 4 * k + 1; }
            if (v.z > best) { best = v.z; bi = 4 * k + 2; }
            if (v.w > best) { best = v.w; bi = 4 * k + 3; }
        }
        s_arg[4][j] = bi;
    } else if (tid >= 320 && tid < 352) {
        // wave 5 lanes 0-31: true-box setup (independent of argmax)
        const int j   = tid - 320;
        const int l   = true_left  [b * S + j];
        const int t   = true_top   [b * S + j];
        const int w   = true_width [b * S + j];
        const int h   = true_height[b * S + j];
        const int lab = true_label [b * S + j];
        const int len = true_length[b];
        const int r  = min(63, l + w);
        const int bo = min(63, t + h);
        const bool val = (j < len) && (t < bo) && (l < r);
        unsigned long long xm = 0ull;
        if (val) xm = (~0ull << l) & (~0ull >> (63 - r));
        s_xmask[0][j] = xm;
        s_meta[0][j]  = (val ? 0x80000000u : 0u) |
                        ((unsigned)t << 12) | ((unsigned)bo << 6) | (unsigned)lab;
    } else if (tid >= 352 && tid < 352 + 3 * NL) {
        (&s_cnt[0][0])[tid - 352] = 0;
    }

    // zero the per-(map,row,label) mask array (3072 u64, 6 per thread)
    {
        unsigned long long* mflat = &s_M[0][0][0];
        #pragma unroll
        for (int k = 0; k < 6; ++k) mflat[tid + k * 512] = 0ull;
    }
    __syncthreads();

    // ---- Phase 2: pred-box setup (needs s_arg) ----
    if (tid < S) {
        const int j   = tid;
        const int l   = s_arg[0][j];
        const int t   = s_arg[1][j];
        const int w   = s_arg[2][j];
        const int h   = s_arg[3][j];
        const int lab = s_arg[4][j];
        const int len = pred_length[b];
        const int r  = min(63, l + w);
        const int bo = min(63, t + h);
        const bool val = (j < len) && (t < bo) && (l < r);
        unsigned long long xm = 0ull;
        if (val) xm = (~0ull << l) & (~0ull >> (63 - r));
        s_xmask[1][j] = xm;
        s_meta[1][j]  = (val ? 0x80000000u : 0u) |
                        ((unsigned)t << 12) | ((unsigned)bo << 6) | (unsigned)lab;
    }
    __syncthreads();

    // ---- Phase 3: painter's sweep per (map,row) → per-label masks ----
    if (tid < 128) {
        const int m = tid >> 6;
        const int y = tid & 63;
        unsigned long long rem = ~0ull;
        #pragma unroll
        for (int j = S - 1; j >= 0; --j) {
            const unsigned int md = s_meta[m][j];
            if (md & 0x80000000u) {
                const int top = (md >> 12) & 63;
                const int bot = (md >> 6)  & 63;
                if (top <= y && y <= bot) {
                    const unsigned long long cov = s_xmask[m][j] & rem;
                    if (cov) {
                        rem &= ~cov;
                        s_M[m][y][md & 31] |= cov;
                    }
                }
            }
        }
        if (rem) s_M[m][y][0] |= rem;   // DEFAULT_LABEL = 0
    }
    __syncthreads();

    // ---- Phase 4: popcount reduction per label (lanes stride labels → no banking) ----
    if (tid < 8 * NL) {
        const int L  = tid % NL;   // consecutive lanes → consecutive labels
        const int rg = tid / NL;   // 8 row-groups
        int ct = 0, cp = 0, ci = 0;
        #pragma unroll
        for (int i = 0; i < 8; ++i) {
            const int y = rg * 8 + i;
            const unsigned long long tm = s_M[0][y][L];
            const unsigned long long pm = s_M[1][y][L];
            ct += __popcll(tm);
            cp += __popcll(pm);
            ci += __popcll(tm & pm);
        }
        atomicAdd(&s_cnt[0][L], ct);
        atomicAdd(&s_cnt[1][L], cp);
        atomicAdd(&s_cnt[2][L], ci);
    }
    __syncthreads();

    // ---- Phase 5: wave-parallel final metrics ----
    if (tid < 64) {
        float it_p = 0.f, ws_p = 0.f, wi_p = 0.f;
        if (tid < NL) {
            const int ct = s_cnt[0][tid];
            const int cp = s_cnt[1][tid];
            const int ci = s_cnt[2][tid];
            const int un = ct + cp - ci;
            it_p = (float)ci;
            if (un > 0) {
                ws_p = 1.f;
                wi_p = (float)ci / ((float)un + 1e-9f);
            }
        }
        #pragma unroll
        for (int m = 32; m >= 1; m >>= 1) {
            it_p += __shfl_xor(it_p, m);
            ws_p += __shfl_xor(ws_p, m);
            wi_p += __shfl_xor(wi_p, m);
        }
        if (tid == 0) {
            out[b]      = it_p / 4096.0f;   // acc
            out[NB + b] = wi_p / ws_p;      // miou
        }
    }
}

extern "C" void kernel_launch(void* const* d_in, const int* in_sizes, int n_in,
                              void* d_out, int out_size, void* d_ws, size_t ws_size,
                              hipStream_t stream) {
    const float* pred_left   = (const float*)d_in[0];
    const float* pred_top    = (const float*)d_in[1];
    const float* pred_width  = (const float*)d_in[2];
    const float* pred_height = (const float*)d_in[3];
    const float* pred_label  = (const float*)d_in[4];
    const int*   true_left   = (const int*)d_in[5];
    const int*   true_top    = (const int*)d_in[6];
    const int*   true_width  = (const int*)d_in[7];
    const int*   true_height = (const int*)d_in[8];
    const int*   true_label  = (const int*)d_in[9];
    const int*   true_length = (const int*)d_in[10];
    const int*   pred_length = (const int*)d_in[11];
    float* out = (float*)d_out;

    layout_metric_kernel<<<NB, 512, 0, stream>>>(
        pred_left, pred_top, pred_width, pred_height, pred_label,
        true_left, true_top, true_width, true_height, true_label,
        true_length, pred_length, out);
}